// Round 7
// baseline (451142.188 us; speedup 1.0000x reference)
//
#include <hip/hip_runtime.h>
#include <math.h>

#define BB 64
#define TT 512
#define II 512
#define HH 512
#define PP 256
#define OO 512
#define IH 1024
#define NBLK 256
#define NTHR 256
#define WPB (NTHR/64)          // 4 waves/block
#define NGRP 8                 // barrier groups

// ---- all mutable state in __device__ globals (fp64 recurrence; zero ws use) ----
__device__ __align__(256) double g_h0[BB*HH];
__device__ __align__(256) double g_h1[BB*HH];
__device__ __align__(256) double g_m0[BB*PP];
__device__ __align__(256) double g_m1[BB*PP];
__device__ __align__(256) double g_u0[BB*HH];
__device__ __align__(256) double g_u1[BB*HH];
__device__ __align__(256) double g_hc0[BB*HH];
__device__ __align__(256) double g_hc1[BB*HH];
__device__ __align__(256) double g_rh0[BB*HH];
__device__ __align__(256) double g_rh1[BB*HH];
__device__ __align__(256) double g_mo0[BB*PP];
__device__ __align__(256) double g_mo1[BB*PP];
__device__ __align__(256) double g_hist[(long)BB*TT*HH];   // fp64 h_mem1 history (134 MB)
__device__ unsigned g_grp[NGRP*64];   // per-group: cnt at [g*64], gen at [g*64+16]
__device__ unsigned g_root[64];       // root: cnt at [0], gen at [16]

struct KP {
  const float *x,*Wr,*br,*Wu,*bu,*Wn,*bn,*Wmr,*bmr,*Wmw,*bmw,*Wmu,*bmu,
              *Wmh,*bmh,*Wd,*bd,*Ws,*bs,*Wout,*bout,*dop,*ser;
  float* out;   // fp32 output buffer (reference output dtype is float32!)
};

__device__ inline double sigd(double x){ return 1.0/(1.0+exp(-x)); }

// fp64-accum dot: A fp32
__device__ inline double dotF(const float* a, const float* w, int K){
  double s0=0,s1=0,s2=0,s3=0;
  #pragma unroll 4
  for (int k=0;k<K;k+=4){
    float4 av = *(const float4*)(a+k);
    float4 wv = *(const float4*)(w+k);
    s0 = fma((double)av.x,(double)wv.x,s0);
    s1 = fma((double)av.y,(double)wv.y,s1);
    s2 = fma((double)av.z,(double)wv.z,s2);
    s3 = fma((double)av.w,(double)wv.w,s3);
  }
  return (s0+s1)+(s2+s3);
}
// fp64-accum dot: A fp64
__device__ inline double dotD(const double* a, const float* w, int K){
  double s0=0,s1=0,s2=0,s3=0;
  #pragma unroll 4
  for (int k=0;k<K;k+=4){
    double2 a0 = *(const double2*)(a+k);
    double2 a1 = *(const double2*)(a+k+2);
    float4 wv = *(const float4*)(w+k);
    s0 = fma(a0.x,(double)wv.x,s0);
    s1 = fma(a0.y,(double)wv.y,s1);
    s2 = fma(a1.x,(double)wv.z,s2);
    s3 = fma(a1.y,(double)wv.w,s3);
  }
  return (s0+s1)+(s2+s3);
}
__device__ inline double dotA(const float* a, const float* w, int K){ return dotF(a,w,K); }
__device__ inline double dotA(const double* a, const float* w, int K){ return dotD(a,w,K); }

// 4 dots sharing one A stream (write-gate quad), fp64
__device__ inline void dot4D(const double* a, const float* w0,const float* w1,
    const float* w2,const float* w3,int K,double& o0,double& o1,double& o2,double& o3){
  double s0=0,s1=0,s2=0,s3=0;
  #pragma unroll 2
  for (int k=0;k<K;k+=2){
    double2 av = *(const double2*)(a+k);
    float2 b0=*(const float2*)(w0+k), b1=*(const float2*)(w1+k),
           b2=*(const float2*)(w2+k), b3=*(const float2*)(w3+k);
    s0 = fma(av.x,(double)b0.x,fma(av.y,(double)b0.y,s0));
    s1 = fma(av.x,(double)b1.x,fma(av.y,(double)b1.y,s1));
    s2 = fma(av.x,(double)b2.x,fma(av.y,(double)b2.y,s2));
    s3 = fma(av.x,(double)b3.x,fma(av.y,(double)b3.y,s3));
  }
  o0=s0;o1=s1;o2=s2;o3=s3;
}

// hierarchical device-scope grid barrier: 32 blocks/group -> 8 groups -> root
// (structure proven correct: round-5 persistent == round-6 serialized, bit-identical)
__device__ inline void gbar(){
  __syncthreads();
  if (threadIdx.x == 0){
    __threadfence();
    int g = blockIdx.x & (NGRP-1);
    unsigned* gcnt = &g_grp[g*64];
    unsigned* ggen = &g_grp[g*64+16];
    unsigned gg  = __hip_atomic_load(ggen, __ATOMIC_RELAXED, __HIP_MEMORY_SCOPE_AGENT);
    unsigned old = __hip_atomic_fetch_add(gcnt, 1u, __ATOMIC_ACQ_REL, __HIP_MEMORY_SCOPE_AGENT);
    if (old == (NBLK/NGRP)-1){
      __hip_atomic_store(gcnt, 0u, __ATOMIC_RELAXED, __HIP_MEMORY_SCOPE_AGENT);
      unsigned* rcnt=&g_root[0]; unsigned* rgen=&g_root[16];
      unsigned rg  = __hip_atomic_load(rgen, __ATOMIC_RELAXED, __HIP_MEMORY_SCOPE_AGENT);
      unsigned ro  = __hip_atomic_fetch_add(rcnt, 1u, __ATOMIC_ACQ_REL, __HIP_MEMORY_SCOPE_AGENT);
      if (ro == NGRP-1){
        __hip_atomic_store(rcnt, 0u, __ATOMIC_RELAXED, __HIP_MEMORY_SCOPE_AGENT);
        __hip_atomic_fetch_add(rgen, 1u, __ATOMIC_RELEASE, __HIP_MEMORY_SCOPE_AGENT);
      } else {
        while (__hip_atomic_load(rgen, __ATOMIC_ACQUIRE, __HIP_MEMORY_SCOPE_AGENT) == rg)
          __builtin_amdgcn_s_sleep(1);
      }
      __hip_atomic_fetch_add(ggen, 1u, __ATOMIC_RELEASE, __HIP_MEMORY_SCOPE_AGENT);
    } else {
      while (__hip_atomic_load(ggen, __ATOMIC_ACQUIRE, __HIP_MEMORY_SCOPE_AGENT) == gg)
        __builtin_amdgcn_s_sleep(1);
    }
    __threadfence();
  }
  __syncthreads();
}

// ---- per-wave jobs: 16(M) x 4(N) tiles; lane -> (m=lane&15, n=lane>>4) ----

template<typename TA>
__device__ inline void job_ru(int job,int lane,const TA* A1,long a1rs,
    const double* hf,const float* Wr_l,const float* Wu_l,const float* br_l,const float* bu_l,
    double* rh,double* uf)
{
  int gate = job>>9, rest = job&511;
  int m = (rest>>7)*16 + (lane&15);
  int col = (rest&127)*4 + (lane>>4);
  const float* wrow = (gate ? Wu_l : Wr_l) + (long)col*IH;
  double acc = dotA(A1 + (long)m*a1rs, wrow, II) + dotD(hf + (long)m*HH, wrow+II, HH);
  double s = sigd(acc + (double)(gate ? bu_l : br_l)[col]);
  long idx = (long)m*HH + col;
  if (gate) uf[idx] = s;
  else      rh[idx] = s * hf[idx];
}

template<typename TA>
__device__ inline void job_n(int job,int lane,const TA* A1,long a1rs,
    const double* rh,const double* uf,const double* hf,const float* Wn_l,const float* bn_l,
    double* hcf)
{
  int m = (job>>7)*16 + (lane&15);
  int col = (job&127)*4 + (lane>>4);
  const float* wrow = Wn_l + (long)col*IH;
  double acc = dotA(A1 + (long)m*a1rs, wrow, II) + dotD(rh + (long)m*HH, wrow+II, HH);
  double n = tanh(acc + (double)bn_l[col]);
  long idx = (long)m*HH + col;
  double u = uf[idx];
  hcf[idx] = (1.0 - u)*hf[idx] + u*n;
}

__device__ inline void job_rg(int job,int lane,const double* hcf,
    const float* Wmr_l,const float* bmr_l,const double* mf,double* mo)
{
  int m = (job>>6)*16 + (lane&15);
  int pcol = (job&63)*4 + (lane>>4);
  double acc = dotD(hcf + (long)m*HH, Wmr_l + (long)pcol*HH, HH);
  long idx = (long)m*PP + pcol;
  mo[idx] = sigd(acc + (double)bmr_l[pcol]) * mf[idx];
}

__device__ inline void job_hm(int job,int lane,const double* mo,
    const float* Wmh_l,const float* bmh_l,const double* hcf,double* hof,
    double* hist,int t)
{
  int m = (job>>7)*16 + (lane&15);
  int col = (job&127)*4 + (lane>>4);
  double acc = dotD(mo + (long)m*PP, Wmh_l + (long)col*PP, PP);
  long idx = (long)m*HH + col;
  double hm = acc + (double)bmh_l[col] + hcf[idx];
  hof[idx] = hm;
  if (hist) hist[((long)m*TT + t)*HH + col] = hm;
}

__device__ inline void job_mg(int job,int lane,const double* A,
    const float* Wmw_l,const float* Wmu_l,const float* Wd_l,const float* Ws_l,
    const float* bmw_l,const float* bmu_l,const float* bd_l,const float* bs_l,
    double dopa,double sero,double* mf)
{
  int m = (job>>6)*16 + (lane&15);
  int pcol = (job&63)*4 + (lane>>4);
  const double* a = A + (long)m*HH;
  long wr = (long)pcol*HH;
  double p0,p1,p2,p3;
  dot4D(a, Wmw_l+wr, Wmu_l+wr, Wd_l+wr, Ws_l+wr, HH, p0,p1,p2,p3);
  double wg = sigd(p0 + (double)bmw_l[pcol]);
  double nm = tanh(p1 + (double)bmu_l[pcol]);
  double dp = sigd((p2 + (double)bd_l[pcol])*dopa);
  double sr = sigd((p3 + (double)bs_l[pcol])*sero);
  double w = wg*dp*(1.0 - sr);
  long idx = (long)m*PP + pcol;
  mf[idx] = (1.0 - w)*mf[idx] + w*nm;
}

__global__ void __launch_bounds__(NTHR) rnn_kernel(KP p)
{
  const int tid = threadIdx.x;
  const int w = blockIdx.x*WPB + (tid>>6);
  const int lane = tid & 63;

  {
    int gid = blockIdx.x*NTHR + tid;
    const int GS = NBLK*NTHR;
    for (int i=gid;i<BB*HH;i+=GS){ g_h0[i]=0.0; g_h1[i]=0.0; }
    for (int i=gid;i<BB*PP;i+=GS){ g_m0[i]=0.0; g_m1[i]=0.0; }
  }
  gbar();

  const float *Wr0=p.Wr,  *Wr1=p.Wr + (long)HH*IH;
  const float *Wu0=p.Wu,  *Wu1=p.Wu + (long)HH*IH;
  const float *Wn0=p.Wn,  *Wn1=p.Wn + (long)HH*IH;
  const float *br0=p.br,  *br1=p.br+HH;
  const float *bu0=p.bu,  *bu1=p.bu+HH;
  const float *bn0=p.bn,  *bn1=p.bn+HH;
  const float *Wmr0=p.Wmr, *Wmr1=p.Wmr+(long)PP*HH;
  const float *bmr0=p.bmr, *bmr1=p.bmr+PP;
  const float *Wmw0=p.Wmw, *Wmw1=p.Wmw+(long)PP*HH;
  const float *bmw0=p.bmw, *bmw1=p.bmw+PP;
  const float *Wmu0=p.Wmu, *Wmu1=p.Wmu+(long)PP*HH;
  const float *bmu0=p.bmu, *bmu1=p.bmu+PP;
  const float *Wd0=p.Wd,   *Wd1=p.Wd+(long)PP*HH;
  const float *bd0=p.bd,   *bd1=p.bd+PP;
  const float *Ws0=p.Ws,   *Ws1=p.Ws+(long)PP*HH;
  const float *bs0=p.bs,   *bs1=p.bs+PP;
  const float *Wmh0=p.Wmh, *Wmh1=p.Wmh+(long)HH*PP;
  const float *bmh0=p.bmh, *bmh1=p.bmh+HH;
  const double dopa = (double)p.dop[0];
  const double sero = (double)p.ser[0];

  for (int t=0; t<TT; ++t){
    const float* xt = p.x + (long)t*II;
    // S1: r0,u0 from [x_t, h0]  |  deferred m1 update for t-1 (reads g_h1 = h_mem1(t-1))
    if (w < 768){
      job_ru(w,     lane, xt, (long)TT*II, g_h0, Wr0,Wu0,br0,bu0, g_rh0, g_u0);
      if (w < 256)
        job_ru(w+768, lane, xt, (long)TT*II, g_h0, Wr0,Wu0,br0,bu0, g_rh0, g_u0);
    } else if (t > 0){
      job_mg(w-768, lane, g_h1, Wmw1,Wmu1,Wd1,Ws1, bmw1,bmu1,bd1,bs1, dopa,sero, g_m1);
    }
    gbar();
    // S2: n0 -> h_cand0
    if (w < 512) job_n(w, lane, xt, (long)TT*II, g_rh0, g_u0, g_h0, Wn0, bn0, g_hc0);
    gbar();
    // S3: read gate 0 -> mem_out0
    if (w < 256) job_rg(w, lane, g_hc0, Wmr0, bmr0, g_m0, g_mo0);
    gbar();
    // S4: h_mem0 (becomes h0 and layer-1 input)
    if (w < 512) job_hm(w, lane, g_mo0, Wmh0, bmh0, g_hc0, g_h0, (double*)nullptr, t);
    gbar();
    // S5: r1,u1 from [h_mem0, h1]  |  m0 update (reads h_mem0(t))
    if (w < 768){
      job_ru(w,     lane, g_h0, (long)HH, g_h1, Wr1,Wu1,br1,bu1, g_rh1, g_u1);
      if (w < 256)
        job_ru(w+768, lane, g_h0, (long)HH, g_h1, Wr1,Wu1,br1,bu1, g_rh1, g_u1);
    } else {
      job_mg(w-768, lane, g_h0, Wmw0,Wmu0,Wd0,Ws0, bmw0,bmu0,bd0,bs0, dopa,sero, g_m0);
    }
    gbar();
    // S6: n1 -> h_cand1
    if (w < 512) job_n(w, lane, g_h0, (long)HH, g_rh1, g_u1, g_h1, Wn1, bn1, g_hc1);
    gbar();
    // S7: read gate 1 -> mem_out1
    if (w < 256) job_rg(w, lane, g_hc1, Wmr1, bmr1, g_m1, g_mo1);
    gbar();
    // S8: h_mem1 (becomes h1; fp64 history for the deferred out projection)
    if (w < 512) job_hm(w, lane, g_mo1, Wmh1, bmh1, g_hc1, g_h1, g_hist, t);
    gbar();
  }
  // flush deferred m1 update for t = TT-1
  if (w < 256) job_mg(w, lane, g_h1, Wmw1,Wmu1,Wd1,Ws1, bmw1,bmu1,bd1,bs1, dopa,sero, g_m1);
  gbar();

  // finals appended after outputs, FP32: h_final [2,B,H], m_final [2,B,P]
  int gid = blockIdx.x*NTHR + tid;
  long obase = (long)BB*TT*OO;
  for (long i=gid; i < 2L*BB*HH; i += (long)NBLK*NTHR){
    double v = (i < (long)BB*HH) ? g_h0[i] : g_h1[i - (long)BB*HH];
    p.out[obase + i] = (float)v;
  }
  long mb = obase + 2L*BB*HH;
  for (long i=gid; i < 2L*BB*PP; i += (long)NBLK*NTHR){
    double v = (i < (long)BB*PP) ? g_m0[i] : g_m1[i - (long)BB*PP];
    p.out[mb + i] = (float)v;
  }
}

// outputs[b,t,:] = Wout @ h_mem1[b,t,:] + bout  (fp64 accum, FP32 store)
__global__ void __launch_bounds__(NTHR) out_gemm(const float* Wout, const float* bout, float* out)
{
  int w = blockIdx.x*WPB + (threadIdx.x>>6);
  int lane = threadIdx.x & 63;
  const int NW = 2048*WPB;
  for (int job = w; job < (BB*TT/16)*(OO/4); job += NW){
    int r   = (job>>7)*16 + (lane&15);        // r = b*T + t
    int col = (job&127)*4 + (lane>>4);
    double acc = dotD(g_hist + (long)r*HH, Wout + (long)col*HH, HH);
    out[(long)r*OO + col] = (float)(acc + (double)bout[col]);
  }
}

extern "C" void kernel_launch(void* const* d_in, const int* in_sizes, int n_in,
                              void* d_out, int out_size, void* d_ws, size_t ws_size,
                              hipStream_t stream)
{
  KP p;
  p.x   = (const float*)d_in[0];
  p.Wr  = (const float*)d_in[1];  p.br  = (const float*)d_in[2];
  p.Wu  = (const float*)d_in[3];  p.bu  = (const float*)d_in[4];
  p.Wn  = (const float*)d_in[5];  p.bn  = (const float*)d_in[6];
  p.Wmr = (const float*)d_in[7];  p.bmr = (const float*)d_in[8];
  p.Wmw = (const float*)d_in[9];  p.bmw = (const float*)d_in[10];
  p.Wmu = (const float*)d_in[11]; p.bmu = (const float*)d_in[12];
  p.Wmh = (const float*)d_in[13]; p.bmh = (const float*)d_in[14];
  p.Wd  = (const float*)d_in[15]; p.bd  = (const float*)d_in[16];
  p.Ws  = (const float*)d_in[17]; p.bs  = (const float*)d_in[18];
  p.Wout= (const float*)d_in[19]; p.bout= (const float*)d_in[20];
  p.dop = (const float*)d_in[21]; p.ser = (const float*)d_in[22];
  p.out = (float*)d_out;          // reference output dtype = float32

  rnn_kernel<<<dim3(NBLK), dim3(NTHR), 0, stream>>>(p);
  out_gemm<<<dim3(2048), dim3(NTHR), 0, stream>>>(p.Wout, p.bout, p.out);
}